// Round 5
// baseline (175.831 us; speedup 1.0000x reference)
//
#include <hip/hip_runtime.h>

// Problem constants: T=16, H=1280, W=1280, N=64 boxes.
#define TT 16
#define HH 1280
#define WW 1280
#define NBOX 64
#define W4 (WW / 4)             // 320 float4 per row
#define SLICE4 (HH * W4)        // 409600 float4 per T-slice

typedef float f32x4 __attribute__((ext_vector_type(4)));

// Fused kernel (R5): mask computation folded into the sum kernel, K1
// eliminated. Proven structure kept from R3 (best, 154.8us): 16-deep
// forced-MLP load batch, sched_barrier(0), __launch_bounds__(256,6)
// -> 6 blocks/CU, plain temporal loads (R4 isolated nt: +3.1us).
//
// Ordering matters:
//   1. stage 64 boxes -> LDS, __syncthreads  (barrier's vmcnt drain only
//      covers this 1KB load -- data batch not yet issued)
//   2. issue the 16 dwordx4 data loads
//   3. sched_barrier(0): loads pinned above, all 16 outstanding
//   4. 64-box VALU loop computes the 4 per-column box counts WHILE the
//      loads are in flight (~18k cyc/SIMD VALU vs ~37k cyc/CU HBM drain
//      at 6 waves/SIMD -> fully hidden)
//   5. FMA consumption waits vmcnt as loads arrive
//
// Weight identity: w_j(y,x_j) = #boxes containing (y,x_j)
//                             = sum_b [by1<=y<by2]*[bx1<=x_j<bx2].
__global__ void __launch_bounds__(256, 6)
fused_boxsum_kernel(const f32x4* __restrict__ data,
                    const int4* __restrict__ boxes,
                    float* __restrict__ out) {
    __shared__ int4 sbox[NBOX];
    int tid = threadIdx.x;
    if (tid < NBOX) sbox[tid] = boxes[tid];     // (x1, y1, x2, y2)
    __syncthreads();

    int idx = blockIdx.x * 256 + tid;           // exactly SLICE4 threads
    int y  = idx / W4;
    int x4 = idx - y * W4;
    int x0 = x4 * 4;                            // first of 4 columns

    const f32x4* p = data + idx;
    f32x4 v[TT];
#pragma unroll
    for (int t = 0; t < TT; ++t)
        v[t] = p[t * SLICE4];                   // 16 independent dwordx4

    // Hard scheduling fence: loads stay above; everything below overlaps
    // their latency.
    __builtin_amdgcn_sched_barrier(0);

    int c0 = 0, c1 = 0, c2 = 0, c3 = 0;
#pragma unroll 2
    for (int b = 0; b < NBOX; ++b) {
        int4 bb = sbox[b];                      // LDS broadcast (uniform addr)
        int inrow = (bb.y <= y) & (y < bb.w);
        c0 += inrow & (bb.x <= x0 + 0) & (x0 + 0 < bb.z);
        c1 += inrow & (bb.x <= x0 + 1) & (x0 + 1 < bb.z);
        c2 += inrow & (bb.x <= x0 + 2) & (x0 + 2 < bb.z);
        c3 += inrow & (bb.x <= x0 + 3) & (x0 + 3 < bb.z);
    }
    float w0 = (float)c0, w1 = (float)c1, w2 = (float)c2, w3 = (float)c3;

    float a0 = 0.f, a1 = 0.f, a2 = 0.f, a3 = 0.f;
#pragma unroll
    for (int t = 0; t < TT; t += 4) {
        a0 += v[t + 0].x * w0 + v[t + 0].y * w1 + v[t + 0].z * w2 + v[t + 0].w * w3;
        a1 += v[t + 1].x * w0 + v[t + 1].y * w1 + v[t + 1].z * w2 + v[t + 1].w * w3;
        a2 += v[t + 2].x * w0 + v[t + 2].y * w1 + v[t + 2].z * w2 + v[t + 2].w * w3;
        a3 += v[t + 3].x * w0 + v[t + 3].y * w1 + v[t + 3].z * w2 + v[t + 3].w * w3;
    }
    float acc = (a0 + a1) + (a2 + a3);

    // 64-lane wave shuffle reduction -> LDS -> one atomic per block.
#pragma unroll
    for (int off = 32; off > 0; off >>= 1)
        acc += __shfl_down(acc, off, 64);

    __shared__ float wsum[4];
    int lane = threadIdx.x & 63;
    int wid  = threadIdx.x >> 6;
    if (lane == 0) wsum[wid] = acc;
    __syncthreads();
    if (threadIdx.x == 0) {
        float s = (wsum[0] + wsum[1]) + (wsum[2] + wsum[3]);
        atomicAdd(out, s);
    }
}

extern "C" void kernel_launch(void* const* d_in, const int* in_sizes, int n_in,
                              void* d_out, int out_size, void* d_ws, size_t ws_size,
                              hipStream_t stream) {
    const float* data = (const float*)d_in[0];        // (T,H,W) float32
    const int* boxes  = (const int*)d_in[1];          // (N,4) int32
    float* out = (float*)d_out;                       // scalar (poisoned)

    hipMemsetAsync(out, 0, sizeof(float), stream);    // graph-safe
    fused_boxsum_kernel<<<SLICE4 / 256, 256, 0, stream>>>(
        (const f32x4*)data, (const int4*)boxes, out);
}

// Round 6
// 156.488 us; speedup vs baseline: 1.1236x; 1.1236x over previous
//
#include <hip/hip_runtime.h>

// Problem constants: T=16, H=1280, W=1280, N=64 boxes.
#define TT 16
#define HH 1280
#define WW 1280
#define NBOX 64
#define W4 (WW / 4)             // 320 float4 per row
#define SLICE4 (HH * W4)        // 409600 float4 per T-slice

// K1: build row/col membership bitmasks (one bit per box) in d_ws, and
// zero the output scalar (fused memset; stream order guarantees it lands
// before any K2 atomicAdd).
// NOTE (R5 evidence): do NOT fuse this into K2. The fused mask loop keeps
// ~20 extra VGPRs live across the 64-VGPR load batch, busting the
// launch_bounds(256,6) cap of 85 -> allocator spills the batch to scratch
// (VGPR=40, 32MB scratch writes, 64us @ 1.58 TB/s).
__global__ void build_masks_kernel(const int* __restrict__ boxes,
                                   unsigned long long* __restrict__ rowmask,
                                   unsigned long long* __restrict__ colmask,
                                   float* __restrict__ out) {
    __shared__ int bx1[NBOX], by1[NBOX], bx2[NBOX], by2[NBOX];
    int tid = threadIdx.x;
    if (tid < NBOX) {
        int4 b = ((const int4*)boxes)[tid];   // (x1, y1, x2, y2)
        bx1[tid] = b.x; by1[tid] = b.y; bx2[tid] = b.z; by2[tid] = b.w;
    }
    if (blockIdx.x == 0 && tid == 0) *out = 0.f;
    __syncthreads();
    int g = blockIdx.x * 256 + tid;           // 0..2559
    if (g < HH) {
        int y = g;
        unsigned long long m = 0ull;
#pragma unroll
        for (int b = 0; b < NBOX; ++b)
            if (by1[b] <= y && y < by2[b]) m |= (1ull << b);
        rowmask[y] = m;
    } else if (g < HH + WW) {
        int x = g - HH;
        unsigned long long m = 0ull;
#pragma unroll
        for (int b = 0; b < NBOX; ++b)
            if (bx1[b] <= x && x < bx2[b]) m |= (1ull << b);
        colmask[x] = m;
    }
}

// K2: R8 structure + FORCED memory-level parallelism, occupancy-fixed.
// (Best measured: 154.8us total, R3.) 16-deep load batch per thread;
// sched_barrier(0) keeps all 16 loads outstanding at the first consumer.
// __launch_bounds__(256, 6): VGPR cap 85 -> 6 blocks/CU -> 1536/1600
// blocks resident; live set (~84) fits EXACTLY -- any extra liveness
// across the batch spills (R5). Plain temporal loads: nt isolated in R4
// at +3.1us (forfeits real cross-iteration L3 hits -- R5's FETCH=67MB
// < 105MB proves partial L3 residency of the input).
__global__ void __launch_bounds__(256, 6)
weighted_sum_kernel(const float4* __restrict__ data,
                    const unsigned long long* __restrict__ rowmask,
                    const longlong2* __restrict__ colmask2,
                    float* __restrict__ out) {
    int idx = blockIdx.x * 256 + threadIdx.x;     // exactly SLICE4 threads
    int y  = idx / W4;
    int x4 = idx - y * W4;

    // Mask loads issued first; their latency overlaps the data-load batch.
    unsigned long long rm = rowmask[y];
    longlong2 c01 = colmask2[x4 * 2 + 0];         // colmask[4*x4 + 0,1]
    longlong2 c23 = colmask2[x4 * 2 + 1];         // colmask[4*x4 + 2,3]

    const float4* p = data + idx;
    float4 v[TT];
#pragma unroll
    for (int t = 0; t < TT; ++t)
        v[t] = p[t * SLICE4];                     // 16 independent dwordx4

    // Hard scheduling fence: nothing moves across. All 16 loads are
    // outstanding when the first consumer below is scheduled.
    __builtin_amdgcn_sched_barrier(0);

    float w0 = (float)__popcll(rm & (unsigned long long)c01.x);
    float w1 = (float)__popcll(rm & (unsigned long long)c01.y);
    float w2 = (float)__popcll(rm & (unsigned long long)c23.x);
    float w3 = (float)__popcll(rm & (unsigned long long)c23.y);

    float a0 = 0.f, a1 = 0.f, a2 = 0.f, a3 = 0.f;
#pragma unroll
    for (int t = 0; t < TT; t += 4) {
        a0 += v[t + 0].x * w0 + v[t + 0].y * w1 + v[t + 0].z * w2 + v[t + 0].w * w3;
        a1 += v[t + 1].x * w0 + v[t + 1].y * w1 + v[t + 1].z * w2 + v[t + 1].w * w3;
        a2 += v[t + 2].x * w0 + v[t + 2].y * w1 + v[t + 2].z * w2 + v[t + 2].w * w3;
        a3 += v[t + 3].x * w0 + v[t + 3].y * w1 + v[t + 3].z * w2 + v[t + 3].w * w3;
    }
    float acc = (a0 + a1) + (a2 + a3);

    // 64-lane wave shuffle reduction -> LDS -> one atomic per block.
#pragma unroll
    for (int off = 32; off > 0; off >>= 1)
        acc += __shfl_down(acc, off, 64);

    __shared__ float wsum[4];
    int lane = threadIdx.x & 63;
    int wid  = threadIdx.x >> 6;
    if (lane == 0) wsum[wid] = acc;
    __syncthreads();
    if (threadIdx.x == 0) {
        float s = (wsum[0] + wsum[1]) + (wsum[2] + wsum[3]);
        atomicAdd(out, s);
    }
}

extern "C" void kernel_launch(void* const* d_in, const int* in_sizes, int n_in,
                              void* d_out, int out_size, void* d_ws, size_t ws_size,
                              hipStream_t stream) {
    const float* data = (const float*)d_in[0];        // (T,H,W) float32
    const int* boxes  = (const int*)d_in[1];          // (N,4) int32
    float* out = (float*)d_out;                       // scalar (poisoned)

    // d_ws: rowmask[1280] u64, colmask[1280] u64 (colmask 16B-aligned).
    unsigned long long* rowmask = (unsigned long long*)d_ws;
    unsigned long long* colmask = rowmask + HH;

    build_masks_kernel<<<10, 256, 0, stream>>>(boxes, rowmask, colmask, out);
    weighted_sum_kernel<<<SLICE4 / 256, 256, 0, stream>>>(
        (const float4*)data, rowmask, (const longlong2*)colmask, out);
}